// Round 10
// baseline (125.854 us; speedup 1.0000x reference)
//
#include <hip/hip_runtime.h>
#include <cstdint>
#include <cstddef>

typedef __bf16 bf16x8 __attribute__((ext_vector_type(8)));
typedef float f32x4 __attribute__((ext_vector_type(4)));

#define MFMA16(a, b, c) __builtin_amdgcn_mfma_f32_16x16x32_bf16(a, b, c, 0, 0, 0)

static __device__ __forceinline__ bf16x8 ld_bf16x8(const __bf16* p) {
    return *reinterpret_cast<const bf16x8*>(p);
}

static __device__ __forceinline__ void async_cp16(const __bf16* g, __bf16* l) {
    __builtin_amdgcn_global_load_lds((const __attribute__((address_space(1))) void*)g,
                                     (__attribute__((address_space(3))) void*)l, 16, 0, 0);
}

template <int N>
static __device__ __forceinline__ void wait_vmcnt() {
    asm volatile("s_waitcnt vmcnt(%0)" ::"n"(N) : "memory");
}

static __device__ __forceinline__ void barrier_pinned() {
    __builtin_amdgcn_sched_barrier(0);
    __builtin_amdgcn_s_barrier();
    __builtin_amdgcn_sched_barrier(0);
}

static __device__ __forceinline__ float ex2(float x) {
    return __builtin_amdgcn_exp2f(x);  // native v_exp_f32 (bf16-tolerant accuracy)
}

// ---- DPP 16-lane rotate-reduce (pure VALU, no DS pipe) ----
template <int CTRL>
static __device__ __forceinline__ float dppmv(float x) {
    return __builtin_bit_cast(float, __builtin_amdgcn_update_dpp(
        0, __builtin_bit_cast(int, x), CTRL, 0xF, 0xF, true));
}
static __device__ __forceinline__ float rmax16(float x) {
    x = fmaxf(x, dppmv<0x121>(x));
    x = fmaxf(x, dppmv<0x122>(x));
    x = fmaxf(x, dppmv<0x124>(x));
    x = fmaxf(x, dppmv<0x128>(x));
    return x;
}
static __device__ __forceinline__ float rsum16(float x) {
    x += dppmv<0x121>(x);
    x += dppmv<0x122>(x);
    x += dppmv<0x124>(x);
    x += dppmv<0x128>(x);
    return x;
}

// ---------------- f32 -> bf16 convert (8 elems/thread) ----------------
__global__ void cvt_kernel(const float* __restrict__ src, __bf16* __restrict__ dst, int n8) {
    int i = blockIdx.x * blockDim.x + threadIdx.x;
    if (i >= n8) return;
    const float4* s4 = reinterpret_cast<const float4*>(src) + (size_t)i * 2;
    float4 a = s4[0], b = s4[1];
    bf16x8 o;
    o[0] = (__bf16)a.x; o[1] = (__bf16)a.y; o[2] = (__bf16)a.z; o[3] = (__bf16)a.w;
    o[4] = (__bf16)b.x; o[5] = (__bf16)b.y; o[6] = (__bf16)b.z; o[7] = (__bf16)b.w;
    reinterpret_cast<bf16x8*>(dst)[i] = o;
}

// ---------------- transpose-convert: in [K][N] f32 -> out [N][K] bf16 ----------------
__global__ __launch_bounds__(256) void tcvt_kernel(const float* __restrict__ in,
                                                   __bf16* __restrict__ out, int K, int N) {
    __shared__ __bf16 T[64][72];
    const int k0 = blockIdx.y * 64, n0 = blockIdx.x * 64;
    const int t = threadIdx.x;
    const int col = (t & 15) << 2;
    const int rowb = t >> 4;
    #pragma unroll
    for (int i = 0; i < 4; i++) {
        int row = i * 16 + rowb;
        float4 v = *reinterpret_cast<const float4*>(&in[(size_t)(k0 + row) * N + n0 + col]);
        T[col + 0][row] = (__bf16)v.x;
        T[col + 1][row] = (__bf16)v.y;
        T[col + 2][row] = (__bf16)v.z;
        T[col + 3][row] = (__bf16)v.w;
    }
    __syncthreads();
    const int oc = (t & 7) << 3;
    const int orb = t >> 3;
    #pragma unroll
    for (int i = 0; i < 2; i++) {
        int r = i * 32 + orb;
        bf16x8 v = *reinterpret_cast<bf16x8*>(&T[r][oc]);
        *reinterpret_cast<bf16x8*>(&out[(size_t)(n0 + r) * K + k0 + oc]) = v;
    }
}

// ---------------- 3-buffer depth-2 counted-vmcnt mainloop, chunk-XOR swizzled ----------
template <int BM, int BN, int WM, int WN>
__device__ __forceinline__ void mainloop2(const __bf16* __restrict__ A,
                                          const __bf16* __restrict__ Bt,
                                          int K, int row0, int col0,
                                          __bf16* lds,
                                          f32x4 (&acc)[BM / WM / 16][BN / WN / 16]) {
    constexpr int MR = BM / WM / 16, NR = BN / WN / 16;
    constexpr int AE = BM * 32;
    constexpr int BUFE = AE + BN * 32;
    constexpr int APW = BM / 16 / 8;
    constexpr int BPW = BN / 16 / 8;
    const int tid = threadIdx.x, l = tid & 63, w = tid >> 6;
    const int wm = w / WN, wn = w % WN;
    const int lr = l >> 2;
    const int lcs = (((l & 3) ^ ((l >> 3) & 3)) << 3);  // pre-swizzled source k-offset
    const int fr = l & 15;
    const int fc = (((l >> 4) ^ ((l >> 1) & 3)) << 3);  // swizzled read k-offset

    const size_t arow = (size_t)(row0 + lr) * K + lcs;
    const size_t brow = (size_t)(col0 + lr) * K + lcs;
    const int nt = K >> 5;

    auto stage = [&](int t, int buf) {
        const int k0 = t << 5;
        const int bb = buf * BUFE;
        #pragma unroll
        for (int j = 0; j < APW; j++) {
            const int mi = w * APW + j;
            async_cp16(A + arow + (size_t)mi * 16 * K + k0, lds + bb + mi * 512 + l * 8);
        }
        #pragma unroll
        for (int j = 0; j < BPW; j++) {
            const int ni = w * BPW + j;
            async_cp16(Bt + brow + (size_t)ni * 16 * K + k0, lds + bb + AE + ni * 512 + l * 8);
        }
    };

    stage(0, 0);
    stage(1, 1);

    const int aoff = (wm * (BM / WM) + fr) * 32 + fc;
    const int boff = AE + (wn * (BN / WN) + fr) * 32 + fc;

    int p = 0;
    for (int t = 0; t < nt; ++t) {
        if (t + 1 < nt) {
            wait_vmcnt<APW + BPW>();
        } else {
            wait_vmcnt<0>();
        }
        barrier_pinned();
        if (t + 2 < nt) {
            int p2 = p + 2; if (p2 >= 3) p2 -= 3;
            stage(t + 2, p2);
        }
        const int cb = p * BUFE;
        bf16x8 af[MR], bfv[NR];
        #pragma unroll
        for (int m = 0; m < MR; m++) af[m] = ld_bf16x8(&lds[cb + aoff + m * 512]);
        #pragma unroll
        for (int n = 0; n < NR; n++) bfv[n] = ld_bf16x8(&lds[cb + boff + n * 512]);
        __builtin_amdgcn_s_setprio(1);
        #pragma unroll
        for (int m = 0; m < MR; m++) {
            #pragma unroll
            for (int n = 0; n < NR; n++) {
                acc[m][n] = MFMA16(af[m], bfv[n], acc[m][n]);
            }
        }
        __builtin_amdgcn_s_setprio(0);
        asm volatile("s_waitcnt lgkmcnt(0)" ::: "memory");
        __builtin_amdgcn_sched_barrier(0);
        p = (p == 2) ? 0 : p + 1;
    }
}

// ---------------- QKV GEMM: x(4096x1024) @ w_attn^T(3072x1024) + b_attn ----------------
// 256x128 tile (16 MFMA/wave/K-step, halves weight re-fetch), grid 24x16.
__global__ __launch_bounds__(512, 2) void gemm_qkv_kernel(const __bf16* __restrict__ xb,
                                                          const __bf16* __restrict__ wabt,
                                                          const float* __restrict__ bias,
                                                          __bf16* __restrict__ qb,
                                                          __bf16* __restrict__ kb,
                                                          __bf16* __restrict__ vt,
                                                          float* __restrict__ present) {
    __shared__ __bf16 lds[3 * (256 * 32 + 128 * 32)];  // 72 KB
    f32x4 acc[4][4] = {};
    const int row0 = blockIdx.y * 256, col0 = blockIdx.x * 128;
    mainloop2<256, 128, 4, 2>(xb, wabt, 1024, row0, col0, lds, acc);

    const int l = threadIdx.x & 63, w = threadIdx.x >> 6;
    const int wm = w >> 1, wn = w & 1;
    const int part = col0 >> 10;  // uniform per block: 0=q 1=k 2=v
    #pragma unroll
    for (int n = 0; n < 4; n++) {
        int col = col0 + wn * 64 + n * 16 + (l & 15);
        int hh = (col >> 6) & 15;
        int dd = col & 63;
        float bv = bias[col];
        #pragma unroll
        for (int m = 0; m < 4; m++) {
            #pragma unroll
            for (int r = 0; r < 4; r++) {
                int row = row0 + wm * 64 + m * 16 + ((l >> 4) << 2) + r;
                int bb = row >> 11, ss = row & 2047;
                float val = acc[m][n][r] + bv;
                size_t qi = (((size_t)(bb * 16 + hh)) * 2048 + ss) * 64 + dd;
                if (part == 0) {
                    qb[qi] = (__bf16)val;
                } else if (part == 1) {
                    kb[qi] = (__bf16)val;
                    present[(((size_t)((bb * 2 + 0) * 16 + hh)) * 2048 + ss) * 64 + dd] = val;
                } else {
                    vt[(((size_t)(bb * 16 + hh)) * 64 + dd) * 2048 + ss] = (__bf16)val;
                    present[(((size_t)((bb * 2 + 1) * 16 + hh)) * 2048 + ss) * 64 + dd] = val;
                }
            }
        }
    }
}

// ---------------- Proj GEMM: a(4096x1024) @ w_proj^T(1024x1024) + b_proj ----------------
__global__ __launch_bounds__(512, 2) void gemm_proj_kernel(const __bf16* __restrict__ ab,
                                                           const __bf16* __restrict__ wpbt,
                                                           const float* __restrict__ bias,
                                                           float* __restrict__ out) {
    __shared__ __bf16 lds[3 * (128 * 32 + 128 * 32)];
    f32x4 acc[2][4] = {};
    const int row0 = blockIdx.y * 128, col0 = blockIdx.x * 128;
    mainloop2<128, 128, 4, 2>(ab, wpbt, 1024, row0, col0, lds, acc);

    const int lane = threadIdx.x & 63, w = threadIdx.x >> 6;
    const int wm = w >> 1, wn = w & 1;
    #pragma unroll
    for (int n = 0; n < 4; n++) {
        int col = col0 + wn * 64 + n * 16 + (lane & 15);
        float bv = bias[col];
        #pragma unroll
        for (int m = 0; m < 2; m++) {
            #pragma unroll
            for (int r = 0; r < 4; r++) {
                int row = row0 + wm * 32 + m * 16 + ((lane >> 4) << 2) + r;
                out[(size_t)row * 1024 + col] = acc[m][n][r] + bv;
            }
        }
    }
}

// ---------------- sliding-window causal flash attention ----------------
// 4 waves/block, 16 q-rows/wave, 64-key tiles. XCD head-grouped swizzle,
// native-exp2 DPP softmax, defer-max, V loads hidden under QK+softmax.
__global__ __launch_bounds__(256) void attn_kernel(const __bf16* __restrict__ qb,
                                                   const __bf16* __restrict__ kb,
                                                   const __bf16* __restrict__ vtb,
                                                   __bf16* __restrict__ ab) {
    __shared__ __bf16 Pls[4][16 * 72];
    const int bidx = blockIdx.x;
    const int xcd = bidx & 7, idx = bidx >> 3;
    const int bh = (xcd << 2) | (idx & 3);
    const int qt = idx >> 2;
    const int lane = threadIdx.x & 63, wid = threadIdx.x >> 6;
    const int q0w = qt * 64 + wid * 16;

    const __bf16* Qh = qb + (size_t)bh * 2048 * 64;
    const __bf16* Kh = kb + (size_t)bh * 2048 * 64;
    const __bf16* Vt = vtb + (size_t)bh * 64 * 2048;
    __bf16* Pw = &Pls[wid][0];

    const int ld16 = lane & 15, hi3 = (lane >> 4) << 3;

    bf16x8 qf[2];
    {
        const __bf16* qp = Qh + (size_t)(q0w + ld16) * 64 + hi3;
        qf[0] = ld_bf16x8(qp);
        qf[1] = ld_bf16x8(qp + 32);
    }

    f32x4 o[4];
    #pragma unroll
    for (int dt = 0; dt < 4; dt++) o[dt] = (f32x4){0.f, 0.f, 0.f, 0.f};
    float mrun[4] = {-1e30f, -1e30f, -1e30f, -1e30f};  // log2-domain
    float srun[4] = {0.f, 0.f, 0.f, 0.f};

    const float cl2 = 0.18033688f;  // (1/sqrt(64)) * log2(e)
    int klo = q0w - 255;
    int kt0 = klo > 0 ? (klo & ~63) : 0;
    const int ktend = q0w + 15;

    for (int kt = kt0; kt <= ktend; kt += 64) {
        // ---- K loads (8 frags) then V loads (8 frags; consumed at PV, latency
        //      hides under QK MFMA + softmax) ----
        bf16x8 kf[4][2];
        #pragma unroll
        for (int kc = 0; kc < 4; kc++) {
            const __bf16* kp = Kh + (size_t)(kt + kc * 16 + ld16) * 64 + hi3;
            kf[kc][0] = ld_bf16x8(kp);
            kf[kc][1] = ld_bf16x8(kp + 32);
        }
        bf16x8 va[4], vb[4];
        #pragma unroll
        for (int dt = 0; dt < 4; dt++) {
            const __bf16* vp = &Vt[(size_t)(dt * 16 + ld16) * 2048 + kt + hi3];
            va[dt] = ld_bf16x8(vp);
            vb[dt] = ld_bf16x8(vp + 32);
        }
        // ---- scores for 64 keys ----
        f32x4 s[4];
        __builtin_amdgcn_s_setprio(1);
        #pragma unroll
        for (int kc = 0; kc < 4; kc++) {
            f32x4 a = (f32x4){0.f, 0.f, 0.f, 0.f};
            a = MFMA16(qf[0], kf[kc][0], a);
            a = MFMA16(qf[1], kf[kc][1], a);
            s[kc] = a;
        }
        __builtin_amdgcn_s_setprio(0);
        // ---- online softmax over 64 keys (log2-domain, native exp2) ----
        const bool clean = (kt >= q0w - 240) && (kt + 63 <= q0w);  // wave-uniform
        float pv0[4], pv1[4], pv2[4], pv3[4];
        if (clean) {
            float mxs[4];
            #pragma unroll
            for (int r = 0; r < 4; r++) {
                float m = fmaxf(fmaxf(s[0][r], s[1][r]), fmaxf(s[2][r], s[3][r]));
                mxs[r] = rmax16(m) * cl2;
            }
            float grow = fmaxf(fmaxf(mxs[0] - mrun[0], mxs[1] - mrun[1]),
                               fmaxf(mxs[2] - mrun[2], mxs[3] - mrun[3]));
            if (__all(grow <= 8.f)) {
                // defer-max: keep old max; P bounded by 2^8; skip o-rescale
                #pragma unroll
                for (int r = 0; r < 4; r++) {
                    float p0 = ex2(s[0][r] * cl2 - mrun[r]);
                    float p1 = ex2(s[1][r] * cl2 - mrun[r]);
                    float p2 = ex2(s[2][r] * cl2 - mrun[r]);
                    float p3 = ex2(s[3][r] * cl2 - mrun[r]);
                    srun[r] += rsum16((p0 + p1) + (p2 + p3));
                    pv0[r] = p0; pv1[r] = p1; pv2[r] = p2; pv3[r] = p3;
                }
            } else {
                float factor[4];
                #pragma unroll
                for (int r = 0; r < 4; r++) {
                    float mn = fmaxf(mrun[r], mxs[r]);
                    float f = ex2(mrun[r] - mn);
                    float p0 = ex2(s[0][r] * cl2 - mn);
                    float p1 = ex2(s[1][r] * cl2 - mn);
                    float p2 = ex2(s[2][r] * cl2 - mn);
                    float p3 = ex2(s[3][r] * cl2 - mn);
                    srun[r] = srun[r] * f + rsum16((p0 + p1) + (p2 + p3));
                    mrun[r] = mn;
                    factor[r] = f;
                    pv0[r] = p0; pv1[r] = p1; pv2[r] = p2; pv3[r] = p3;
                }
                #pragma unroll
                for (int dt = 0; dt < 4; dt++) {
                    #pragma unroll
                    for (int r = 0; r < 4; r++) o[dt][r] *= factor[r];
                }
            }
        } else {
            float factor[4];
            #pragma unroll
            for (int r = 0; r < 4; r++) {
                int q = q0w + ((lane >> 4) << 2) + r;
                int kb0 = kt + ld16;
                bool ok0 = (kb0 <= q) && (kb0 > q - 256);
                bool ok1 = (kb0 + 16 <= q) && (kb0 + 16 > q - 256);
                bool ok2 = (kb0 + 32 <= q) && (kb0 + 32 > q - 256);
                bool ok3 = (kb0 + 48 <= q) && (kb0 + 48 > q - 256);
                float t0 = ok0 ? s[0][r] * cl2 : -1e30f;
                float t1 = ok1 ? s[1][r] * cl2 : -1e30f;
                float t2 = ok2 ? s[2][r] * cl2 : -1e30f;
                float t3 = ok3 ? s[3][r] * cl2 : -1e30f;
                float mx = rmax16(fmaxf(fmaxf(t0, t1), fmaxf(t2, t3)));
                float mn = fmaxf(mrun[r], mx);
                float f = ex2(mrun[r] - mn);
                float p0 = ok0 ? ex2(t0 - mn) : 0.f;
                float p1 = ok1 ? ex2(t1 - mn) : 0.f;
                float p2 = ok2 ? ex2(t2 - mn) : 0.f;
                float p3 = ok3 ? ex2(t3 - mn) : 0.f;
                srun[r] = srun[r] * f + rsum16((p0 + p1) + (p2 + p3));
                mrun[r] = mn;
                factor[r] = f;
                pv0[r] = p0; pv1[r] = p1; pv2[r] = p2; pv3[r] = p3;
            }
            #pragma unroll
            for (int dt = 0; dt < 4; dt++) {
                #pragma unroll
                for (int r = 0; r < 4; r++) o[dt][r] *= factor[r];
            }
        }
        // ---- write P (16x64) to per-wave LDS, pad 72 ----
        #pragma unroll
        for (int r = 0; r < 4; r++) {
            int qrow = ((lane >> 4) << 2) + r;
            Pw[qrow * 72 + ld16]      = (__bf16)pv0[r];
            Pw[qrow * 72 + 16 + ld16] = (__bf16)pv1[r];
            Pw[qrow * 72 + 32 + ld16] = (__bf16)pv2[r];
            Pw[qrow * 72 + 48 + ld16] = (__bf16)pv3[r];
        }
        asm volatile("s_waitcnt lgkmcnt(0)" ::: "memory");
        // ---- PV: o(16x64) += P(16x64) * V(64x64) ----
        bf16x8 pfA = ld_bf16x8(&Pw[ld16 * 72 + hi3]);
        bf16x8 pfB = ld_bf16x8(&Pw[ld16 * 72 + 32 + hi3]);
        __builtin_amdgcn_s_setprio(1);
        #pragma unroll
        for (int dt = 0; dt < 4; dt++) o[dt] = MFMA16(pfA, va[dt], o[dt]);
        #pragma unroll
        for (int dt = 0; dt < 4; dt++) o[dt] = MFMA16(pfB, vb[dt], o[dt]);
        __builtin_amdgcn_s_setprio(0);
    }

    const int bb = bh >> 4, hh = bh & 15;
    #pragma unroll
    for (int r = 0; r < 4; r++) {
        int q = q0w + ((lane >> 4) << 2) + r;
        float inv = 1.f / srun[r];
        size_t base = ((size_t)bb * 2048 + q) * 1024 + hh * 64;
        #pragma unroll
        for (int dt = 0; dt < 4; dt++) {
            ab[base + dt * 16 + ld16] = (__bf16)(o[dt][r] * inv);
        }
    }
}

// ---------------- launch ----------------
extern "C" void kernel_launch(void* const* d_in, const int* in_sizes, int n_in,
                              void* d_out, int out_size, void* d_ws, size_t ws_size,
                              hipStream_t stream) {
    const float* x = (const float*)d_in[0];
    const float* w_attn = (const float*)d_in[1];
    const float* b_attn = (const float*)d_in[2];
    const float* w_proj = (const float*)d_in[3];
    const float* b_proj = (const float*)d_in[4];

    float* out = (float*)d_out;
    float* present = out + (size_t)2 * 2048 * 1024;

    char* w = (char*)d_ws;
    __bf16* xb   = (__bf16*)(w);
    __bf16* wabt = (__bf16*)(w + 8388608);
    __bf16* wpbt = (__bf16*)(w + 14680064);
    __bf16* qb   = (__bf16*)(w + 16777216);
    __bf16* kb   = (__bf16*)(w + 25165824);
    __bf16* vt   = (__bf16*)(w + 33554432);
    __bf16* ab   = xb;

    cvt_kernel<<<2048, 256, 0, stream>>>(x, xb, 524288);
    tcvt_kernel<<<dim3(48, 16), 256, 0, stream>>>(w_attn, wabt, 1024, 3072);
    tcvt_kernel<<<dim3(16, 16), 256, 0, stream>>>(w_proj, wpbt, 1024, 1024);

    gemm_qkv_kernel<<<dim3(24, 16), 512, 0, stream>>>(xb, wabt, b_attn, qb, kb, vt, present);

    attn_kernel<<<1024, 256, 0, stream>>>(qb, kb, vt, ab);

    gemm_proj_kernel<<<dim3(8, 32), 512, 0, stream>>>(ab, wpbt, b_proj, out);
}

// Round 11
// 119.975 us; speedup vs baseline: 1.0490x; 1.0490x over previous
//
#include <hip/hip_runtime.h>
#include <cstdint>
#include <cstddef>

typedef __bf16 bf16x8 __attribute__((ext_vector_type(8)));
typedef float f32x4 __attribute__((ext_vector_type(4)));

#define MFMA16(a, b, c) __builtin_amdgcn_mfma_f32_16x16x32_bf16(a, b, c, 0, 0, 0)

static __device__ __forceinline__ bf16x8 ld_bf16x8(const __bf16* p) {
    return *reinterpret_cast<const bf16x8*>(p);
}

static __device__ __forceinline__ void async_cp16(const __bf16* g, __bf16* l) {
    __builtin_amdgcn_global_load_lds((const __attribute__((address_space(1))) void*)g,
                                     (__attribute__((address_space(3))) void*)l, 16, 0, 0);
}

template <int N>
static __device__ __forceinline__ void wait_vmcnt() {
    asm volatile("s_waitcnt vmcnt(%0)" ::"n"(N) : "memory");
}

static __device__ __forceinline__ void barrier_pinned() {
    __builtin_amdgcn_sched_barrier(0);
    __builtin_amdgcn_s_barrier();
    __builtin_amdgcn_sched_barrier(0);
}

static __device__ __forceinline__ float ex2(float x) {
    return __builtin_amdgcn_exp2f(x);  // native v_exp_f32
}

// ---- DPP 16-lane rotate-reduce (pure VALU, no DS pipe) ----
template <int CTRL>
static __device__ __forceinline__ float dppmv(float x) {
    return __builtin_bit_cast(float, __builtin_amdgcn_update_dpp(
        0, __builtin_bit_cast(int, x), CTRL, 0xF, 0xF, true));
}
static __device__ __forceinline__ float rmax16(float x) {
    x = fmaxf(x, dppmv<0x121>(x));
    x = fmaxf(x, dppmv<0x122>(x));
    x = fmaxf(x, dppmv<0x124>(x));
    x = fmaxf(x, dppmv<0x128>(x));
    return x;
}
static __device__ __forceinline__ float rsum16(float x) {
    x += dppmv<0x121>(x);
    x += dppmv<0x122>(x);
    x += dppmv<0x124>(x);
    x += dppmv<0x128>(x);
    return x;
}

// ---------------- f32 -> bf16 convert (8 elems/thread) ----------------
__global__ void cvt_kernel(const float* __restrict__ src, __bf16* __restrict__ dst, int n8) {
    int i = blockIdx.x * blockDim.x + threadIdx.x;
    if (i >= n8) return;
    const float4* s4 = reinterpret_cast<const float4*>(src) + (size_t)i * 2;
    float4 a = s4[0], b = s4[1];
    bf16x8 o;
    o[0] = (__bf16)a.x; o[1] = (__bf16)a.y; o[2] = (__bf16)a.z; o[3] = (__bf16)a.w;
    o[4] = (__bf16)b.x; o[5] = (__bf16)b.y; o[6] = (__bf16)b.z; o[7] = (__bf16)b.w;
    reinterpret_cast<bf16x8*>(dst)[i] = o;
}

// ---------------- transpose-convert: in [K][N] f32 -> out [N][K] bf16 ----------------
__global__ __launch_bounds__(256) void tcvt_kernel(const float* __restrict__ in,
                                                   __bf16* __restrict__ out, int K, int N) {
    __shared__ __bf16 T[64][72];
    const int k0 = blockIdx.y * 64, n0 = blockIdx.x * 64;
    const int t = threadIdx.x;
    const int col = (t & 15) << 2;
    const int rowb = t >> 4;
    #pragma unroll
    for (int i = 0; i < 4; i++) {
        int row = i * 16 + rowb;
        float4 v = *reinterpret_cast<const float4*>(&in[(size_t)(k0 + row) * N + n0 + col]);
        T[col + 0][row] = (__bf16)v.x;
        T[col + 1][row] = (__bf16)v.y;
        T[col + 2][row] = (__bf16)v.z;
        T[col + 3][row] = (__bf16)v.w;
    }
    __syncthreads();
    const int oc = (t & 7) << 3;
    const int orb = t >> 3;
    #pragma unroll
    for (int i = 0; i < 2; i++) {
        int r = i * 32 + orb;
        bf16x8 v = *reinterpret_cast<bf16x8*>(&T[r][oc]);
        *reinterpret_cast<bf16x8*>(&out[(size_t)(n0 + r) * K + k0 + oc]) = v;
    }
}

// ---------------- 3-buffer depth-2 counted-vmcnt mainloop, chunk-XOR swizzled ----------
template <int BM, int BN, int WM, int WN>
__device__ __forceinline__ void mainloop2(const __bf16* __restrict__ A,
                                          const __bf16* __restrict__ Bt,
                                          int K, int row0, int col0,
                                          __bf16* lds,
                                          f32x4 (&acc)[BM / WM / 16][BN / WN / 16]) {
    constexpr int MR = BM / WM / 16, NR = BN / WN / 16;
    constexpr int AE = BM * 32;
    constexpr int BUFE = AE + BN * 32;
    constexpr int APW = BM / 16 / 8;
    constexpr int BPW = BN / 16 / 8;
    const int tid = threadIdx.x, l = tid & 63, w = tid >> 6;
    const int wm = w / WN, wn = w % WN;
    const int lr = l >> 2;
    const int lcs = (((l & 3) ^ ((l >> 3) & 3)) << 3);  // pre-swizzled source k-offset
    const int fr = l & 15;
    const int fc = (((l >> 4) ^ ((l >> 1) & 3)) << 3);  // swizzled read k-offset

    const size_t arow = (size_t)(row0 + lr) * K + lcs;
    const size_t brow = (size_t)(col0 + lr) * K + lcs;
    const int nt = K >> 5;

    auto stage = [&](int t, int buf) {
        const int k0 = t << 5;
        const int bb = buf * BUFE;
        #pragma unroll
        for (int j = 0; j < APW; j++) {
            const int mi = w * APW + j;
            async_cp16(A + arow + (size_t)mi * 16 * K + k0, lds + bb + mi * 512 + l * 8);
        }
        #pragma unroll
        for (int j = 0; j < BPW; j++) {
            const int ni = w * BPW + j;
            async_cp16(Bt + brow + (size_t)ni * 16 * K + k0, lds + bb + AE + ni * 512 + l * 8);
        }
    };

    stage(0, 0);
    stage(1, 1);

    const int aoff = (wm * (BM / WM) + fr) * 32 + fc;
    const int boff = AE + (wn * (BN / WN) + fr) * 32 + fc;

    int p = 0;
    for (int t = 0; t < nt; ++t) {
        if (t + 1 < nt) {
            wait_vmcnt<APW + BPW>();
        } else {
            wait_vmcnt<0>();
        }
        barrier_pinned();
        if (t + 2 < nt) {
            int p2 = p + 2; if (p2 >= 3) p2 -= 3;
            stage(t + 2, p2);
        }
        const int cb = p * BUFE;
        bf16x8 af[MR], bfv[NR];
        #pragma unroll
        for (int m = 0; m < MR; m++) af[m] = ld_bf16x8(&lds[cb + aoff + m * 512]);
        #pragma unroll
        for (int n = 0; n < NR; n++) bfv[n] = ld_bf16x8(&lds[cb + boff + n * 512]);
        __builtin_amdgcn_s_setprio(1);
        #pragma unroll
        for (int m = 0; m < MR; m++) {
            #pragma unroll
            for (int n = 0; n < NR; n++) {
                acc[m][n] = MFMA16(af[m], bfv[n], acc[m][n]);
            }
        }
        __builtin_amdgcn_s_setprio(0);
        asm volatile("s_waitcnt lgkmcnt(0)" ::: "memory");
        __builtin_amdgcn_sched_barrier(0);
        p = (p == 2) ? 0 : p + 1;
    }
}

// ---------------- QKV GEMM: x(4096x1024) @ w_attn^T(3072x1024) + b_attn ----------------
// R9 config: 128x128 tile, 512 threads, grid 24x32 = 768 blocks (measured 47.6us).
__global__ __launch_bounds__(512, 2) void gemm_qkv_kernel(const __bf16* __restrict__ xb,
                                                          const __bf16* __restrict__ wabt,
                                                          const float* __restrict__ bias,
                                                          __bf16* __restrict__ qb,
                                                          __bf16* __restrict__ kb,
                                                          __bf16* __restrict__ vt,
                                                          float* __restrict__ present) {
    __shared__ __bf16 lds[3 * (128 * 32 + 128 * 32)];  // 48 KB
    f32x4 acc[2][4] = {};
    const int row0 = blockIdx.y * 128, col0 = blockIdx.x * 128;
    mainloop2<128, 128, 4, 2>(xb, wabt, 1024, row0, col0, lds, acc);

    const int l = threadIdx.x & 63, w = threadIdx.x >> 6;
    const int wm = w >> 1, wn = w & 1;
    const int part = col0 >> 10;  // uniform per block: 0=q 1=k 2=v
    #pragma unroll
    for (int n = 0; n < 4; n++) {
        int col = col0 + wn * 64 + n * 16 + (l & 15);
        int hh = (col >> 6) & 15;
        int dd = col & 63;
        float bv = bias[col];
        #pragma unroll
        for (int m = 0; m < 2; m++) {
            #pragma unroll
            for (int r = 0; r < 4; r++) {
                int row = row0 + wm * 32 + m * 16 + ((l >> 4) << 2) + r;
                int bb = row >> 11, ss = row & 2047;
                float val = acc[m][n][r] + bv;
                size_t qi = (((size_t)(bb * 16 + hh)) * 2048 + ss) * 64 + dd;
                if (part == 0) {
                    qb[qi] = (__bf16)val;
                } else if (part == 1) {
                    kb[qi] = (__bf16)val;
                    present[(((size_t)((bb * 2 + 0) * 16 + hh)) * 2048 + ss) * 64 + dd] = val;
                } else {
                    vt[(((size_t)(bb * 16 + hh)) * 64 + dd) * 2048 + ss] = (__bf16)val;
                    present[(((size_t)((bb * 2 + 1) * 16 + hh)) * 2048 + ss) * 64 + dd] = val;
                }
            }
        }
    }
}

// ---------------- Proj GEMM: a(4096x1024) @ w_proj^T(1024x1024) + b_proj ----------------
__global__ __launch_bounds__(512, 2) void gemm_proj_kernel(const __bf16* __restrict__ ab,
                                                           const __bf16* __restrict__ wpbt,
                                                           const float* __restrict__ bias,
                                                           float* __restrict__ out) {
    __shared__ __bf16 lds[3 * (128 * 32 + 128 * 32)];
    f32x4 acc[2][4] = {};
    const int row0 = blockIdx.y * 128, col0 = blockIdx.x * 128;
    mainloop2<128, 128, 4, 2>(ab, wpbt, 1024, row0, col0, lds, acc);

    const int lane = threadIdx.x & 63, w = threadIdx.x >> 6;
    const int wm = w >> 1, wn = w & 1;
    #pragma unroll
    for (int n = 0; n < 4; n++) {
        int col = col0 + wn * 64 + n * 16 + (lane & 15);
        float bv = bias[col];
        #pragma unroll
        for (int m = 0; m < 2; m++) {
            #pragma unroll
            for (int r = 0; r < 4; r++) {
                int row = row0 + wm * 32 + m * 16 + ((lane >> 4) << 2) + r;
                out[(size_t)row * 1024 + col] = acc[m][n][r] + bv;
            }
        }
    }
}

// ---------------- sliding-window causal flash attention, split-K ----------------
// Block = 32 q-rows: 2 q-tiles(16 rows) x 2 window-halves. Each wave runs online
// softmax over its half (even/odd 64-key tiles); halves merge via LDS. 8192 waves
// total -> 2x occupancy and half the per-wave serial chain vs R10.
__global__ __launch_bounds__(256) void attn_kernel(const __bf16* __restrict__ qb,
                                                   const __bf16* __restrict__ kb,
                                                   const __bf16* __restrict__ vtb,
                                                   __bf16* __restrict__ ab) {
    __shared__ __bf16 Pls[4][16 * 72];   // per-wave P tile
    __shared__ float combsh[2176];       // o[2][16][66] + m[2][16] + s[2][16]
    const int bidx = blockIdx.x;
    const int xcd = bidx & 7, idx = bidx >> 3;
    const int bh = (xcd << 2) | (idx & 3);  // 4 heads per XCD (K+V L2-resident)
    const int qt = idx >> 2;                // 32-row q-tile, 0..63
    const int lane = threadIdx.x & 63, wid = threadIdx.x >> 6;
    const int qsub = wid >> 1, half = wid & 1;
    const int q0w = qt * 32 + qsub * 16;

    const __bf16* Qh = qb + (size_t)bh * 2048 * 64;
    const __bf16* Kh = kb + (size_t)bh * 2048 * 64;
    const __bf16* Vt = vtb + (size_t)bh * 64 * 2048;
    __bf16* Pw = &Pls[wid][0];

    const int ld16 = lane & 15, hi3 = (lane >> 4) << 3, hi4 = (lane >> 4) << 2;

    bf16x8 qf[2];
    {
        const __bf16* qp = Qh + (size_t)(q0w + ld16) * 64 + hi3;
        qf[0] = ld_bf16x8(qp);
        qf[1] = ld_bf16x8(qp + 32);
    }

    f32x4 o[4];
    #pragma unroll
    for (int dt = 0; dt < 4; dt++) o[dt] = (f32x4){0.f, 0.f, 0.f, 0.f};
    float mrun[4] = {-1e30f, -1e30f, -1e30f, -1e30f};  // log2-domain
    float srun[4] = {0.f, 0.f, 0.f, 0.f};

    const float cl2 = 0.18033688f;  // (1/sqrt(64)) * log2(e)
    int klo = q0w - 255;
    int kt0 = klo > 0 ? (klo & ~63) : 0;
    const int ktend = q0w + 15;

    for (int kt = kt0 + half * 64; kt <= ktend; kt += 128) {
        bf16x8 kf[4][2];
        #pragma unroll
        for (int kc = 0; kc < 4; kc++) {
            const __bf16* kp = Kh + (size_t)(kt + kc * 16 + ld16) * 64 + hi3;
            kf[kc][0] = ld_bf16x8(kp);
            kf[kc][1] = ld_bf16x8(kp + 32);
        }
        bf16x8 va[4], vb[4];
        #pragma unroll
        for (int dt = 0; dt < 4; dt++) {
            const __bf16* vp = &Vt[(size_t)(dt * 16 + ld16) * 2048 + kt + hi3];
            va[dt] = ld_bf16x8(vp);
            vb[dt] = ld_bf16x8(vp + 32);
        }
        // ---- scores for 64 keys ----
        f32x4 s[4];
        __builtin_amdgcn_s_setprio(1);
        #pragma unroll
        for (int kc = 0; kc < 4; kc++) {
            f32x4 a = (f32x4){0.f, 0.f, 0.f, 0.f};
            a = MFMA16(qf[0], kf[kc][0], a);
            a = MFMA16(qf[1], kf[kc][1], a);
            s[kc] = a;
        }
        __builtin_amdgcn_s_setprio(0);
        // ---- online softmax over 64 keys ----
        const bool clean = (kt >= q0w - 240) && (kt + 63 <= q0w);  // wave-uniform
        float pv0[4], pv1[4], pv2[4], pv3[4];
        if (clean) {
            float mxs[4];
            #pragma unroll
            for (int r = 0; r < 4; r++) {
                float m = fmaxf(fmaxf(s[0][r], s[1][r]), fmaxf(s[2][r], s[3][r]));
                mxs[r] = rmax16(m) * cl2;
            }
            float grow = fmaxf(fmaxf(mxs[0] - mrun[0], mxs[1] - mrun[1]),
                               fmaxf(mxs[2] - mrun[2], mxs[3] - mrun[3]));
            if (__all(grow <= 8.f)) {
                #pragma unroll
                for (int r = 0; r < 4; r++) {
                    float p0 = ex2(s[0][r] * cl2 - mrun[r]);
                    float p1 = ex2(s[1][r] * cl2 - mrun[r]);
                    float p2 = ex2(s[2][r] * cl2 - mrun[r]);
                    float p3 = ex2(s[3][r] * cl2 - mrun[r]);
                    srun[r] += rsum16((p0 + p1) + (p2 + p3));
                    pv0[r] = p0; pv1[r] = p1; pv2[r] = p2; pv3[r] = p3;
                }
            } else {
                float factor[4];
                #pragma unroll
                for (int r = 0; r < 4; r++) {
                    float mn = fmaxf(mrun[r], mxs[r]);
                    float f = ex2(mrun[r] - mn);
                    float p0 = ex2(s[0][r] * cl2 - mn);
                    float p1 = ex2(s[1][r] * cl2 - mn);
                    float p2 = ex2(s[2][r] * cl2 - mn);
                    float p3 = ex2(s[3][r] * cl2 - mn);
                    srun[r] = srun[r] * f + rsum16((p0 + p1) + (p2 + p3));
                    mrun[r] = mn;
                    factor[r] = f;
                    pv0[r] = p0; pv1[r] = p1; pv2[r] = p2; pv3[r] = p3;
                }
                #pragma unroll
                for (int dt = 0; dt < 4; dt++) {
                    #pragma unroll
                    for (int r = 0; r < 4; r++) o[dt][r] *= factor[r];
                }
            }
        } else {
            float factor[4];
            #pragma unroll
            for (int r = 0; r < 4; r++) {
                int q = q0w + hi4 + r;
                int kb0 = kt + ld16;
                bool ok0 = (kb0 <= q) && (kb0 > q - 256);
                bool ok1 = (kb0 + 16 <= q) && (kb0 + 16 > q - 256);
                bool ok2 = (kb0 + 32 <= q) && (kb0 + 32 > q - 256);
                bool ok3 = (kb0 + 48 <= q) && (kb0 + 48 > q - 256);
                float t0 = ok0 ? s[0][r] * cl2 : -1e30f;
                float t1 = ok1 ? s[1][r] * cl2 : -1e30f;
                float t2 = ok2 ? s[2][r] * cl2 : -1e30f;
                float t3 = ok3 ? s[3][r] * cl2 : -1e30f;
                float mx = rmax16(fmaxf(fmaxf(t0, t1), fmaxf(t2, t3)));
                float mn = fmaxf(mrun[r], mx);
                float f = ex2(mrun[r] - mn);
                float p0 = ok0 ? ex2(t0 - mn) : 0.f;
                float p1 = ok1 ? ex2(t1 - mn) : 0.f;
                float p2 = ok2 ? ex2(t2 - mn) : 0.f;
                float p3 = ok3 ? ex2(t3 - mn) : 0.f;
                srun[r] = srun[r] * f + rsum16((p0 + p1) + (p2 + p3));
                mrun[r] = mn;
                factor[r] = f;
                pv0[r] = p0; pv1[r] = p1; pv2[r] = p2; pv3[r] = p3;
            }
            #pragma unroll
            for (int dt = 0; dt < 4; dt++) {
                #pragma unroll
                for (int r = 0; r < 4; r++) o[dt][r] *= factor[r];
            }
        }
        // ---- write P (16x64) to per-wave LDS, pad 72 ----
        #pragma unroll
        for (int r = 0; r < 4; r++) {
            int qrow = hi4 + r;
            Pw[qrow * 72 + ld16]      = (__bf16)pv0[r];
            Pw[qrow * 72 + 16 + ld16] = (__bf16)pv1[r];
            Pw[qrow * 72 + 32 + ld16] = (__bf16)pv2[r];
            Pw[qrow * 72 + 48 + ld16] = (__bf16)pv3[r];
        }
        asm volatile("s_waitcnt lgkmcnt(0)" ::: "memory");
        // ---- PV: o(16x64) += P(16x64) * V(64x64) ----
        bf16x8 pfA = ld_bf16x8(&Pw[ld16 * 72 + hi3]);
        bf16x8 pfB = ld_bf16x8(&Pw[ld16 * 72 + 32 + hi3]);
        __builtin_amdgcn_s_setprio(1);
        #pragma unroll
        for (int dt = 0; dt < 4; dt++) o[dt] = MFMA16(pfA, va[dt], o[dt]);
        #pragma unroll
        for (int dt = 0; dt < 4; dt++) o[dt] = MFMA16(pfB, vb[dt], o[dt]);
        __builtin_amdgcn_s_setprio(0);
    }

    // ---- split-K merge: half 1 publishes partials; half 0 merges & stores ----
    if (half == 1) {
        #pragma unroll
        for (int dt = 0; dt < 4; dt++) {
            #pragma unroll
            for (int r = 0; r < 4; r++) {
                combsh[(qsub * 16 + hi4 + r) * 66 + dt * 16 + ld16] = o[dt][r];
            }
        }
        if (ld16 == 0) {
            #pragma unroll
            for (int r = 0; r < 4; r++) {
                combsh[2112 + qsub * 16 + hi4 + r] = mrun[r];
                combsh[2144 + qsub * 16 + hi4 + r] = srun[r];
            }
        }
    }
    __syncthreads();
    if (half == 0) {
        float f0[4], f1[4];
        #pragma unroll
        for (int r = 0; r < 4; r++) {
            float m1 = combsh[2112 + qsub * 16 + hi4 + r];
            float s1 = combsh[2144 + qsub * 16 + hi4 + r];
            float mm = fmaxf(mrun[r], m1);
            f0[r] = ex2(mrun[r] - mm);
            f1[r] = ex2(m1 - mm);
            srun[r] = srun[r] * f0[r] + s1 * f1[r];
        }
        const int bb = bh >> 4, hh = bh & 15;
        #pragma unroll
        for (int r = 0; r < 4; r++) {
            int q = q0w + hi4 + r;
            float inv = 1.f / srun[r];
            size_t base = ((size_t)bb * 2048 + q) * 1024 + hh * 64;
            #pragma unroll
            for (int dt = 0; dt < 4; dt++) {
                float o1 = combsh[(qsub * 16 + hi4 + r) * 66 + dt * 16 + ld16];
                ab[base + dt * 16 + ld16] = (__bf16)((o[dt][r] * f0[r] + o1 * f1[r]) * inv);
            }
        }
    }
}

// ---------------- launch ----------------
extern "C" void kernel_launch(void* const* d_in, const int* in_sizes, int n_in,
                              void* d_out, int out_size, void* d_ws, size_t ws_size,
                              hipStream_t stream) {
    const float* x = (const float*)d_in[0];
    const float* w_attn = (const float*)d_in[1];
    const float* b_attn = (const float*)d_in[2];
    const float* w_proj = (const float*)d_in[3];
    const float* b_proj = (const float*)d_in[4];

    float* out = (float*)d_out;
    float* present = out + (size_t)2 * 2048 * 1024;

    char* w = (char*)d_ws;
    __bf16* xb   = (__bf16*)(w);
    __bf16* wabt = (__bf16*)(w + 8388608);
    __bf16* wpbt = (__bf16*)(w + 14680064);
    __bf16* qb   = (__bf16*)(w + 16777216);
    __bf16* kb   = (__bf16*)(w + 25165824);
    __bf16* vt   = (__bf16*)(w + 33554432);
    __bf16* ab   = xb;

    cvt_kernel<<<2048, 256, 0, stream>>>(x, xb, 524288);
    tcvt_kernel<<<dim3(48, 16), 256, 0, stream>>>(w_attn, wabt, 1024, 3072);
    tcvt_kernel<<<dim3(16, 16), 256, 0, stream>>>(w_proj, wpbt, 1024, 1024);

    gemm_qkv_kernel<<<dim3(24, 32), 512, 0, stream>>>(xb, wabt, b_attn, qb, kb, vt, present);

    attn_kernel<<<2048, 256, 0, stream>>>(qb, kb, vt, ab);

    gemm_proj_kernel<<<dim3(8, 32), 512, 0, stream>>>(ab, wpbt, b_proj, out);
}